// Round 8
// baseline (379.104 us; speedup 1.0000x reference)
//
#include <hip/hip_runtime.h>

// Blocks SNN forward: T=1024, TB=8, B=32, N=1024.
// One thread per (b,n) chain; 128 sequential time-blocks per thread.
// State in f64 to match the harness's float64 numpy reference on every
// heaviside decision (fp32 reassociation flips ~1e-7 margins).
//
// R8: VOLATILE register-frame pipeline. R2/R3/R5/R6/R7 all ~87-100us with
// VGPR proving the prefetch frames were never live: any movable load gets
// sunk to its use (MachineSinking crosses sched_barriers; x is __restrict__
// so nothing blocks it). volatile loads are position-pinned by the memory
// model itself, while the waitcnt pass still emits precise vmcnt(N) only
// before first use. PF=8 rotating f4 frame file (64 VGPRs must appear in
// VGPR_Count), LDS lane-transpose, 2 nontemporal dwordx4 stores per body.

constexpr int T_LEN = 1024;
constexpr int TB    = 8;
constexpr int NBLK  = T_LEN / TB;   // 128
constexpr int BATCH = 32;
constexpr int NOUT  = 1024;
constexpr int BN    = BATCH * NOUT; // 32768 chains
constexpr int PF    = 8;            // prefetch depth (blocks) = frame count

typedef float f4 __attribute__((ext_vector_type(4)));

__global__ __launch_bounds__(64, 1)
void snn_blocks_kernel(const float* __restrict__ x,
                       const float* __restrict__ beta_raw,
                       const float* __restrict__ p_raw,
                       const float* __restrict__ b_raw,
                       float* __restrict__ out)
{
    __shared__ float inbuf[TB][64];   // 2KB: load-transpose staging
    __shared__ float sbuf[TB][64];    // 2KB: store-transpose staging

    const int lane = threadIdx.x;
    const int wg0  = blockIdx.x * 64;       // flat chain offset of this WG
    const int gid  = wg0 + lane;            // = b*NOUT + n
    const int n    = gid & (NOUT - 1);

    // 16B-per-lane split: lane i handles row (i>>4) [+4 for 2nd op],
    // cols (i&15)*4..+3 of the 64-chain stripe.
    const int rowoff = lane >> 4;
    const int coloff = wg0 + (lane & 15) * 4;

    const float* xbase = x + (ptrdiff_t)rowoff * BN + coloff;

    // rotating register frame file (constant-indexed after unrolling).
    // volatile: loads are pinned at issue position; results stay live in
    // VGPRs until consumed 8 bodies later.
    f4 fr[PF][2];

    // preamble FIRST so the initial HBM latency overlaps the param setup
#pragma unroll
    for (int k = 0; k < PF; ++k) {
        fr[k][0] = *(const volatile f4*)(xbase + (ptrdiff_t)(k * TB) * BN);
        fr[k][1] = *(const volatile f4*)(xbase + (ptrdiff_t)(k * TB + 4) * BN);
    }

    // clamped properties (f64)
    double beta = (double)beta_raw[n];
    beta = beta < 0.001 ? 0.001 : (beta > 0.999 ? 0.999 : beta);
    double p = fabs((double)p_raw[n]);
    p = p > 0.999 ? 0.999 : p;
    double bb = fabs((double)b_raw[n]);
    bb = bb < 0.001 ? 0.001 : (bb > 1.0 ? 1.0 : bb);
    const double inv_p = 1.0 / p;

    double ppow[9];                 // p^0 .. p^8
    ppow[0] = 1.0;
#pragma unroll
    for (int i = 1; i <= 8; ++i) ppow[i] = ppow[i - 1] * p;

    double bbp[8];                  // bb * p^(t+1)
#pragma unroll
    for (int t = 0; t < 8; ++t) bbp[t] = bb * ppow[t + 1];

    // carry state
    double m = 0.0;                 // running membrane / int_mem
    double a = 0.0;                 // a_kernel scalar (a_k[t] = p^(t+1)*a)
    int    maskf = 0;               // any spike (z==1) in prev block
    int    decay = 0;               // count(z>1) in prev block
    double ssum  = 0.0;             // sum_t p^(t+1)*spike[t] of prev block
    int    zzero = 0xFF;            // bit t set if prev z[t]==0

    auto body = [&](int blk, f4 v0, f4 v1) {
        // frame -> per-chain transpose via LDS (plain ds ops; compiler
        // inserts precise lgkm waits; same-wave DS executes in order)
        *(f4*)&inbuf[rowoff][(lane & 15) * 4]     = v0;
        *(f4*)&inbuf[rowoff + 4][(lane & 15) * 4] = v1;
        float cur[8];
#pragma unroll
        for (int t = 0; t < 8; ++t) cur[t] = inbuf[t][lane];

        // block header from previous block's stats
        const double a_at = a * ssum + inv_p;
        double pd = 1.0;                        // p^decay, decay in [0,8]
        pd *= (decay & 1) ? p       : 1.0;
        pd *= (decay & 2) ? ppow[2] : 1.0;
        pd *= (decay & 4) ? ppow[4] : 1.0;
        pd *= (decay & 8) ? ppow[8] : 1.0;
        const double new_a = a_at * pd;

        if (maskf) { a = new_a;     m = 0.0; }  // v_init = 0
        else       { a = ppow[8] * a;        }  // keep int_mem

        int nmaskf = 0, ndecay = 0, nzzero = 0;
        double nssum = 0.0;
        int c = 0, zc = 0;
#pragma unroll
        for (int t = 0; t < 8; ++t) {
            double xv = (double)cur[t];
            if (maskf && ((zzero >> t) & 1)) xv = 0.0;  // refractory mask
            m = beta * m + xv;                           // causal decayed sum
            const double vth = 1.0 + bbp[t] * a;         // 1 + bb*p^(t+1)*a
            const int f = (m - vth > 0.0) ? 1 : 0;       // heaviside (strict >)
            c  += f;                                     // cumsum(faulty)
            zc += c;                                     // double cumsum
            nmaskf |= (zc == 1);
            ndecay += (zc > 1) ? 1 : 0;
            nssum  += (zc == 1) ? ppow[t + 1] : 0.0;
            nzzero |= (zc == 0) ? (1 << t) : 0;
            sbuf[t][lane] = (zc == 1) ? 1.0f : 0.0f;     // stage spike
        }
        maskf = nmaskf; decay = ndecay; ssum = nssum; zzero = nzzero;

        // drain staged spikes: 2 x dwordx4 nt stores (lane-transposed)
        const float* sflat = &sbuf[0][0];
        f4 s0 = *(const f4*)(sflat + lane * 4);
        f4 s1 = *(const f4*)(sflat + 256 + lane * 4);
        __builtin_nontemporal_store(
            s0, (f4*)(out + (ptrdiff_t)(blk * TB + rowoff) * BN + coloff));
        __builtin_nontemporal_store(
            s1, (f4*)(out + (ptrdiff_t)(blk * TB + 4 + rowoff) * BN + coloff));
    };

    // steady: body blk consumes fr[blk%8] (volatile-loaded 8 bodies ago),
    // then reloads the slot for blk+8. Program order is pinned by volatile.
#pragma unroll 1
    for (int r = 0; r < NBLK / PF; ++r) {
#pragma unroll
        for (int i = 0; i < PF; ++i) {
            const int blk = r * PF + i;
            body(blk, fr[i][0], fr[i][1]);
            const int pfb = blk + PF;
            if (pfb < NBLK) {
                fr[i][0] = *(const volatile f4*)(xbase + (ptrdiff_t)(pfb * TB) * BN);
                fr[i][1] = *(const volatile f4*)(xbase + (ptrdiff_t)(pfb * TB + 4) * BN);
            }
        }
    }
}

extern "C" void kernel_launch(void* const* d_in, const int* in_sizes, int n_in,
                              void* d_out, int out_size, void* d_ws, size_t ws_size,
                              hipStream_t stream) {
    const float* x        = (const float*)d_in[0];
    const float* beta_raw = (const float*)d_in[1];
    const float* p_raw    = (const float*)d_in[2];
    const float* b_raw    = (const float*)d_in[3];
    float* out            = (float*)d_out;

    dim3 grid(BN / 64);   // 512 workgroups of 1 wave
    dim3 block(64);
    snn_blocks_kernel<<<grid, block, 0, stream>>>(x, beta_raw, p_raw, b_raw, out);
}